// Round 10
// baseline (884.357 us; speedup 1.0000x reference)
//
#include <hip/hip_runtime.h>

#define NB 4
#define NN 2048
#define HIDDEN 256
#define NH 8
#define VD 32

typedef float f4 __attribute__((ext_vector_type(4)));

__device__ __forceinline__ float gelu_f(float v) {
    return 0.5f * v * (1.0f + erff(v * 0.7071067811865475f));
}

// h[b,n,c] = gelu(sum_i x[b,n,i]*w[i,c] + b[c]),  IN_C=3
__global__ void k_encode(const float* __restrict__ x, const float* __restrict__ w,
                         const float* __restrict__ b, float* __restrict__ out) {
    int id = blockIdx.x * 256 + threadIdx.x;
    int c = id & 255, rn = id >> 8;
    float acc = b[c];
    acc += x[rn * 3 + 0] * w[c] + x[rn * 3 + 1] * w[256 + c] + x[rn * 3 + 2] * w[512 + c];
    out[id] = gelu_f(acc);
}

// Per row of m: k-th smallest (radix select), row min, per-head softmax denom.
__global__ __launch_bounds__(256) void k_thrsel(const float* __restrict__ m,
        const float* __restrict__ rv, float* __restrict__ thr,
        float* __restrict__ mmin, float* __restrict__ invD, int kcount)
{
    __shared__ float rowf[NN];
    __shared__ unsigned hist[256];
    __shared__ float redf[32];
    __shared__ unsigned redu[4];
    __shared__ unsigned s_bin, s_below;
    const int row = blockIdx.x, t = threadIdx.x;
    const int lane = t & 63, wid = t >> 6;
    const float* mr = m + (size_t)row * NN;

    float lmin = 3.4e38f;
    for (int i = t; i < NN; i += 256) { float v = mr[i]; rowf[i] = v; lmin = fminf(lmin, v); }
#pragma unroll
    for (int d = 32; d > 0; d >>= 1) lmin = fminf(lmin, __shfl_xor(lmin, d, 64));
    if (lane == 0) redf[wid] = lmin;
    __syncthreads();
    const float rmin = fminf(fminf(redf[0], redf[1]), fminf(redf[2], redf[3]));

    unsigned prefix = 0; int want = kcount;
    const unsigned hmasks[4] = {0u, 0xFF000000u, 0xFFFF0000u, 0xFFFFFF00u};
    for (int pass = 0; pass < 4; ++pass) {
        const int shift = 24 - 8 * pass;
        hist[t] = 0;
        __syncthreads();
        const unsigned hm = hmasks[pass];
        for (int i = t; i < NN; i += 256) {
            unsigned u = __float_as_uint(rowf[i]);
            u ^= (u & 0x80000000u) ? 0xFFFFFFFFu : 0x80000000u;
            if ((u & hm) == (prefix & hm))
                atomicAdd(&hist[(u >> shift) & 255u], 1u);
        }
        __syncthreads();
        const unsigned cnt = hist[t];
        unsigned v = cnt;
#pragma unroll
        for (int d = 1; d < 64; d <<= 1) {
            unsigned o = __shfl_up(v, d, 64);
            if (lane >= d) v += o;
        }
        if (lane == 63) redu[wid] = v;
        __syncthreads();
        unsigned woff = 0;
#pragma unroll
        for (int w = 0; w < 3; w++) if (w < wid) woff += redu[w];
        const unsigned incl = v + woff;
        const unsigned below = incl - cnt;
        if (incl >= (unsigned)want && below < (unsigned)want) { s_bin = (unsigned)t; s_below = below; }
        __syncthreads();
        want -= (int)s_below;
        prefix |= (s_bin << shift);
    }
    unsigned ku = prefix;
    ku = (ku & 0x80000000u) ? (ku & 0x7FFFFFFFu) : ~ku;
    const float tf = __uint_as_float(ku);

    const float cc = (float)(0.25 * 3.141592653589793 * (1.0 - 1e-7));
    float sch[NH], lacc[NH];
#pragma unroll
    for (int h = 0; h < NH; h++) { sch[h] = tanf(cc * (1.0f + sinf(rv[h]))); lacc[h] = 0.f; }
    for (int i = t; i < NN; i += 256) {
        float v = rowf[i];
        if (v <= tf) {
            float d = v - rmin;
#pragma unroll
            for (int h = 0; h < NH; h++) lacc[h] += expf(-sch[h] * d);
        }
    }
#pragma unroll
    for (int h = 0; h < NH; h++) {
#pragma unroll
        for (int d = 32; d > 0; d >>= 1) lacc[h] += __shfl_xor(lacc[h], d, 64);
    }
    if (lane == 0) {
#pragma unroll
        for (int h = 0; h < NH; h++) redf[wid * 8 + h] = lacc[h];
    }
    __syncthreads();
    if (t < NH)
        invD[t * NN + row] = 1.0f / (redf[t] + redf[8 + t] + redf[16 + t] + redf[24 + t]);
    if (t == 0) { thr[row] = tf; mmin[row] = rmin; }
}

// ---------- legacy 64x64 GEMM (fallback when workspace is small) ----------
__global__ __launch_bounds__(256) void k_gemm(const float* __restrict__ A,
        const float* __restrict__ Wm, const float* __restrict__ bias,
        const float* __restrict__ addsrc, float* __restrict__ Cm, int act, int wmode)
{
    __shared__ float AsT[64 * 68];
    __shared__ float Ws[64 * 68];
    const int r0 = blockIdx.x * 64;
    const int c0 = blockIdx.y * 64;
    const int t = threadIdx.x;
    const int ty = t >> 4, tx = t & 15;
    float acc[4][4] = {};
    for (int k0 = 0; k0 < 256; k0 += 64) {
        __syncthreads();
#pragma unroll
        for (int l = 0; l < 16; l++) {
            int lin = l * 256 + t;
            int rr = lin >> 6, kk = lin & 63;
            AsT[kk * 68 + rr] = A[(size_t)(r0 + rr) * 256 + k0 + kk];
            Ws[rr * 68 + kk] = wmode
                ? Wm[(size_t)((c0 + kk) >> 5) * (HIDDEN * VD) + (size_t)(k0 + rr) * VD + ((c0 + kk) & 31)]
                : Wm[(size_t)(k0 + rr) * 256 + c0 + kk];
        }
        __syncthreads();
#pragma unroll 8
        for (int kk = 0; kk < 64; kk++) {
            const float4 a4 = *(const float4*)&AsT[kk * 68 + ty * 4];
            const float4 w4 = *(const float4*)&Ws[kk * 68 + tx * 4];
            float av[4] = {a4.x, a4.y, a4.z, a4.w};
            float wv[4] = {w4.x, w4.y, w4.z, w4.w};
#pragma unroll
            for (int q = 0; q < 4; q++)
#pragma unroll
                for (int p = 0; p < 4; p++)
                    acc[q][p] = fmaf(av[q], wv[p], acc[q][p]);
        }
    }
#pragma unroll
    for (int q = 0; q < 4; q++) {
        int r = r0 + ty * 4 + q;
#pragma unroll
        for (int p = 0; p < 4; p++) {
            int c = c0 + tx * 4 + p;
            float v = acc[q][p];
            if (bias) v += bias[c];
            if (addsrc) v += addsrc[(size_t)r * 256 + c];
            if (act) v = gelu_f(v);
            Cm[(size_t)r * 256 + c] = v;
        }
    }
}

// ---------- split-K GEMM, LEGACY structure (no prefetch registers) ----------
// (r5-r9 lesson: prefetch-register skeleton trips a 128-VGPR allocator cliff
//  -> scratch spill, ~650 MB/dispatch HBM traffic. Stage-direct-to-LDS never
//  spills. Keep this structure.)
template<int WMODE>
__global__ __launch_bounds__(256) void k_gemm9(const float* __restrict__ A,
        const float* __restrict__ Wm, float* __restrict__ G0, float* __restrict__ G1)
{
    __shared__ float AsT[64 * 68];
    __shared__ float Ws[64 * 68];
    const int r0 = blockIdx.x * 64;
    const int c0 = blockIdx.y * 64;
    const int kbase = blockIdx.z * 128;
    float* __restrict__ G = blockIdx.z ? G1 : G0;
    const int t = threadIdx.x;
    const int ty = t >> 4, tx = t & 15;
    float acc[4][4] = {};
    for (int kh = 0; kh < 128; kh += 64) {
        const int k0 = kbase + kh;
        __syncthreads();
#pragma unroll
        for (int l = 0; l < 16; l++) {
            int lin = l * 256 + t;
            int rr = lin >> 6, kk = lin & 63;
            AsT[kk * 68 + rr] = A[(size_t)(r0 + rr) * 256 + k0 + kk];
            Ws[rr * 68 + kk] = WMODE
                ? Wm[(size_t)((c0 + kk) >> 5) * (HIDDEN * VD) + (size_t)(k0 + rr) * VD + ((c0 + kk) & 31)]
                : Wm[(size_t)(k0 + rr) * 256 + c0 + kk];
        }
        __syncthreads();
#pragma unroll 8
        for (int kk = 0; kk < 64; kk++) {
            const float4 a4 = *(const float4*)&AsT[kk * 68 + ty * 4];
            const float4 w4 = *(const float4*)&Ws[kk * 68 + tx * 4];
            float av[4] = {a4.x, a4.y, a4.z, a4.w};
            float wv[4] = {w4.x, w4.y, w4.z, w4.w};
#pragma unroll
            for (int q = 0; q < 4; q++)
#pragma unroll
                for (int p = 0; p < 4; p++)
                    acc[q][p] = fmaf(av[q], wv[p], acc[q][p]);
        }
    }
#pragma unroll
    for (int q = 0; q < 4; q++) {
        const int r = r0 + ty * 4 + q;
        f4 st;
#pragma unroll
        for (int p = 0; p < 4; p++) st[p] = acc[q][p];
        *(f4*)&G[(size_t)r * 256 + c0 + tx * 4] = st;
    }
}

// out = act(g0 + g1 + bias + addsrc)
__global__ __launch_bounds__(256) void k_gemmcomb(const float* __restrict__ g0,
        const float* __restrict__ g1, const float* __restrict__ bias,
        const float* __restrict__ addsrc, float* __restrict__ out, int act)
{
    int gid = blockIdx.x * 256 + threadIdx.x;
    int idx = gid * 4;
    int c = idx & 255;
    f4 a = *(const f4*)&g0[idx];
    f4 b = *(const f4*)&g1[idx];
    f4 s;
#pragma unroll
    for (int k = 0; k < 4; k++) s[k] = a[k] + b[k];
    if (bias) {
        f4 bb = *(const f4*)&bias[c];
#pragma unroll
        for (int k = 0; k < 4; k++) s[k] += bb[k];
    }
    if (addsrc) {
        f4 r = *(const f4*)&addsrc[idx];
#pragma unroll
        for (int k = 0; k < 4; k++) s[k] += r[k];
    }
    if (act) {
#pragma unroll
        for (int k = 0; k < 4; k++) s[k] = gelu_f(s[k]);
    }
    *(f4*)&out[idx] = s;
}

// ---------- att-apply: single-buffered, j-tile 32, up to 8-way j-split ----
// grid: (head*16 + itile, jsplit), 256 threads, i-tile=128, acc 8x8/thread.
// LDS = Es[128][36] + Vs[32][132] = 35.3 KB -> 4 blocks/CU at jsplit 8.
#define TJA 32
__global__ __launch_bounds__(256, 2) void k_attapply7(
    const float* __restrict__ m, const float* __restrict__ v2,
    const float* __restrict__ rv, const float* __restrict__ thr,
    const float* __restrict__ mmin,
    float* __restrict__ P0, float* __restrict__ P1,
    float* __restrict__ P2, float* __restrict__ P3,
    float* __restrict__ P4, float* __restrict__ P5,
    float* __restrict__ P6, float* __restrict__ P7, int jlen)
{
    __shared__ float Es[128 * 36];   // [ii][jj], stride 36
    __shared__ float Vs[TJA * 132];  // [jj][col], stride 132
    const int head = blockIdx.x >> 4;
    const int i0 = (blockIdx.x & 15) * 128;
    const int jbase = blockIdx.y * jlen;
    const int by = blockIdx.y;       // uniform -> SGPR selects, no scratch
    float* __restrict__ P = (by == 0) ? P0 : (by == 1) ? P1 : (by == 2) ? P2
                          : (by == 3) ? P3 : (by == 4) ? P4 : (by == 5) ? P5
                          : (by == 6) ? P6 : P7;
    const int t = threadIdx.x;
    const int tx = t & 15, ty = t >> 4;     // compute: cols {4tx,64+4tx}, rows q*16+ty
    const int txm = t & 7, tym = t >> 3;    // E staging: rows q*32+tym, j 4txm
    const int c4 = t & 31, jw = t >> 5;     // V staging
    const int bbv = c4 >> 3, kkv = (c4 & 7) * 4;
    const float cc = (float)(0.25 * 3.141592653589793 * (1.0 - 1e-7));
    const float scale = tanf(cc * (1.0f + sinf(rv[head])));

    float thr_r[4], mmn_r[4];
#pragma unroll
    for (int q = 0; q < 4; q++) {
        thr_r[q] = thr[i0 + q * 32 + tym];
        mmn_r[q] = mmin[i0 + q * 32 + tym];
    }

    float acc[8][8];
#pragma unroll
    for (int q = 0; q < 8; q++)
#pragma unroll
        for (int p = 0; p < 8; p++) acc[q][p] = 0.f;

    f4 pm[4], pv[4];
    const int NT = jlen / TJA;

#define A_LOAD(S)                                                              \
    do {                                                                       \
        const int j0 = jbase + (S) * TJA;                                      \
        _Pragma("unroll")                                                      \
        for (int q = 0; q < 4; q++)                                            \
            pm[q] = *(const f4*)&m[(size_t)(i0 + q * 32 + tym) * NN + j0 + 4 * txm]; \
        _Pragma("unroll")                                                      \
        for (int l = 0; l < 4; l++)                                            \
            pv[l] = *(const f4*)&v2[(((size_t)bbv * NN) + j0 + l * 8 + jw) * HIDDEN + head * VD + kkv]; \
    } while (0)

#define A_STORE()                                                              \
    do {                                                                       \
        _Pragma("unroll")                                                      \
        for (int q = 0; q < 4; q++) {                                          \
            f4 ev;                                                             \
            _Pragma("unroll")                                                  \
            for (int d = 0; d < 4; d++) {                                      \
                float e = 0.f;                                                 \
                if (pm[q][d] <= thr_r[q]) e = expf(-scale * (pm[q][d] - mmn_r[q])); \
                ev[d] = e;                                                     \
            }                                                                  \
            *(f4*)&Es[(q * 32 + tym) * 36 + 4 * txm] = ev;                     \
        }                                                                      \
        _Pragma("unroll")                                                      \
        for (int l = 0; l < 4; l++)                                            \
            *(f4*)&Vs[(l * 8 + jw) * 132 + 4 * c4] = pv[l];                    \
    } while (0)

    A_LOAD(0);
    A_STORE();
    __syncthreads();

    for (int s = 0; s < NT; s++) {
        if (s + 1 < NT) A_LOAD(s + 1);
        for (int jc = 0; jc < TJA; jc += 4) {
            f4 ev[8], va[4], vb[4];
#pragma unroll
            for (int q = 0; q < 8; q++)
                ev[q] = *(const f4*)&Es[(q * 16 + ty) * 36 + jc];
#pragma unroll
            for (int d = 0; d < 4; d++) {
                va[d] = *(const f4*)&Vs[(jc + d) * 132 + 4 * tx];
                vb[d] = *(const f4*)&Vs[(jc + d) * 132 + 64 + 4 * tx];
            }
#pragma unroll
            for (int d = 0; d < 4; d++) {
#pragma unroll
                for (int q = 0; q < 8; q++) {
                    const float e = ev[q][d];
#pragma unroll
                    for (int p = 0; p < 4; p++) {
                        acc[q][p]     = fmaf(e, va[d][p], acc[q][p]);
                        acc[q][p + 4] = fmaf(e, vb[d][p], acc[q][p + 4]);
                    }
                }
            }
        }
        if (s + 1 < NT) {
            __syncthreads();
            A_STORE();
            __syncthreads();
        }
    }
#undef A_LOAD
#undef A_STORE

    const int bba = tx >> 3, kka = (tx & 7) * 4;
#pragma unroll
    for (int q = 0; q < 8; q++) {
        const int gi = i0 + q * 16 + ty;
        f4 sa, sb;
#pragma unroll
        for (int p = 0; p < 4; p++) { sa[p] = acc[q][p]; sb[p] = acc[q][p + 4]; }
        *(f4*)&P[(((size_t)bba * NN) + gi) * HIDDEN + head * VD + kka] = sa;
        *(f4*)&P[(((size_t)(bba + 2) * NN) + gi) * HIDDEN + head * VD + kka] = sb;
    }
}

// io = gelu((io + p1 [+ p2 + p3 [+ p4..p7]]) * invD[h,i])
__global__ __launch_bounds__(256) void k_attcombine(const float* __restrict__ p1,
        const float* __restrict__ p2, const float* __restrict__ p3,
        const float* __restrict__ p4, const float* __restrict__ p5,
        const float* __restrict__ p6, const float* __restrict__ p7,
        const float* __restrict__ invD, float* __restrict__ io)
{
    int gid = blockIdx.x * 256 + threadIdx.x;
    int idx = gid * 4;
    int hid = idx & (HIDDEN - 1);
    int i = (idx >> 8) & (NN - 1);
    float sD = invD[(hid >> 5) * NN + i];
    f4 a = *(const f4*)&io[idx];
    f4 b = *(const f4*)&p1[idx];
    f4 s;
#pragma unroll
    for (int k = 0; k < 4; k++) s[k] = a[k] + b[k];
    if (p2) {
        f4 c = *(const f4*)&p2[idx];
        f4 d = *(const f4*)&p3[idx];
#pragma unroll
        for (int k = 0; k < 4; k++) s[k] += c[k] + d[k];
    }
    if (p4) {
        f4 c = *(const f4*)&p4[idx];
        f4 d = *(const f4*)&p5[idx];
        f4 e = *(const f4*)&p6[idx];
        f4 f = *(const f4*)&p7[idx];
#pragma unroll
        for (int k = 0; k < 4; k++) s[k] += (c[k] + d[k]) + (e[k] + f[k]);
    }
#pragma unroll
    for (int k = 0; k < 4; k++) s[k] = gelu_f(s[k] * sD);
    *(f4*)&io[idx] = s;
}

// out[row] = sum_c A[row,c]*w[c] + b   (one wave per row)
__global__ void k_decode(const float* __restrict__ a, const float* __restrict__ w,
                         const float* __restrict__ b, float* __restrict__ out) {
    int gid = blockIdx.x * 256 + threadIdx.x;
    int row = gid >> 6, lane = threadIdx.x & 63;
    const float* ar = a + (size_t)row * HIDDEN;
    float s = ar[lane] * w[lane] + ar[lane + 64] * w[lane + 64]
            + ar[lane + 128] * w[lane + 128] + ar[lane + 192] * w[lane + 192];
    for (int off = 32; off > 0; off >>= 1) s += __shfl_down(s, off);
    if (lane == 0) out[row] = s + b[0];
}

extern "C" void kernel_launch(void* const* d_in, const int* in_sizes, int n_in,
                              void* d_out, int out_size, void* d_ws, size_t ws_size,
                              hipStream_t stream)
{
    (void)in_sizes; (void)n_in; (void)out_size;
    const float* x      = (const float*)d_in[0];
    const float* m0     = (const float*)d_in[1];
    const float* m1     = (const float*)d_in[2];
    const float* m2     = (const float*)d_in[3];
    const float* m3     = (const float*)d_in[4];
    const float* en_w   = (const float*)d_in[5];
    const float* en_b   = (const float*)d_in[6];
    const float* down_r = (const float*)d_in[7];
    const float* down_w = (const float*)d_in[8];
    const float* pa0_r  = (const float*)d_in[9];
    const float* pa0_w  = (const float*)d_in[10];
    const float* pa1_r  = (const float*)d_in[11];
    const float* pa1_w  = (const float*)d_in[12];
    const float* mlp0_w1= (const float*)d_in[13];
    const float* mlp0_b1= (const float*)d_in[14];
    const float* mlp0_w2= (const float*)d_in[15];
    const float* mlp0_b2= (const float*)d_in[16];
    const float* w0_w   = (const float*)d_in[17];
    const float* w0_b   = (const float*)d_in[18];
    const float* mlp1_w1= (const float*)d_in[19];
    const float* mlp1_b1= (const float*)d_in[20];
    const float* mlp1_w2= (const float*)d_in[21];
    const float* mlp1_b2= (const float*)d_in[22];
    const float* w1_w   = (const float*)d_in[23];
    const float* w1_b   = (const float*)d_in[24];
    const float* up_r   = (const float*)d_in[25];
    const float* up_w   = (const float*)d_in[26];
    const float* de1_w  = (const float*)d_in[27];
    const float* de1_b  = (const float*)d_in[28];
    const float* de2_w  = (const float*)d_in[29];
    const float* de2_b  = (const float*)d_in[30];
    float* out = (float*)d_out;

    float* WS = (float*)d_ws;
    const size_t SZ = (size_t)NB * NN * HIDDEN;
    float* Hb  = WS;
    float* Ab  = Hb + SZ;
    float* Vb  = Ab + SZ;
    float* T1  = Vb + SZ;
    float* THR = T1 + SZ;       // 2048
    float* MMIN= THR + NN;      // 2048
    float* INVD= MMIN + NN;     // H*N
    float* P2  = INVD + NH * NN;
    float* P3  = P2 + SZ;
    float* P4  = P3 + SZ;
    float* P5  = P4 + SZ;
    float* P6  = P5 + SZ;
    float* P7  = P6 + SZ;
    const size_t need4 = (size_t)((P3 + SZ) - WS) * sizeof(float);
    const size_t need8 = (size_t)((P7 + SZ) - WS) * sizeof(float);
    const int JS = (ws_size >= need8) ? 8 : (ws_size >= need4) ? 4 : 2;
    float* T3  = Vb;            // alias: value buffer dead outside posatt

    // GEMM helper: dst = act(A@W + bias + add); split-K partials in P2/P3
    auto gemm = [&](const float* A, const float* W, const float* bias,
                    const float* add, float* dst, int act, int wmode) {
        if (JS >= 4) {
            if (wmode)
                hipLaunchKernelGGL((k_gemm9<1>), dim3(128, 4, 2), dim3(256), 0, stream,
                                   A, W, P2, P3);
            else
                hipLaunchKernelGGL((k_gemm9<0>), dim3(128, 4, 2), dim3(256), 0, stream,
                                   A, W, P2, P3);
            hipLaunchKernelGGL(k_gemmcomb, dim3((int)(SZ / 4 / 256)), dim3(256), 0, stream,
                               P2, P3, bias, add, dst, act);
        } else {
            hipLaunchKernelGGL(k_gemm, dim3(128, 4), dim3(256), 0, stream,
                               A, W, bias, add, dst, act, wmode);
        }
    };

    auto posatt = [&](const float* src, float* dst2, const float* md,
                      const float* r, const float* w, int kc) {
        hipLaunchKernelGGL(k_thrsel, dim3(NN), dim3(256), 0, stream, md, r, THR, MMIN, INVD, kc);
        gemm(src, w, nullptr, nullptr, Vb, 0, 1);
        hipLaunchKernelGGL(k_attapply7, dim3(128, JS), dim3(256), 0, stream,
                           md, Vb, r, THR, MMIN,
                           dst2, T1, P2, P3, P4, P5, P6, P7, NN / JS);
        hipLaunchKernelGGL(k_attcombine, dim3((int)(SZ / 4 / 256)), dim3(256), 0, stream,
                           T1,
                           (JS >= 4) ? P2 : (const float*)nullptr,
                           (JS >= 4) ? P3 : (const float*)nullptr,
                           (JS == 8) ? P4 : (const float*)nullptr,
                           (JS == 8) ? P5 : (const float*)nullptr,
                           (JS == 8) ? P6 : (const float*)nullptr,
                           (JS == 8) ? P7 : (const float*)nullptr,
                           INVD, dst2);
    };

    float* curH = Hb; float* oth = Ab;
    hipLaunchKernelGGL(k_encode, dim3(8192), dim3(256), 0, stream, x, en_w, en_b, curH);

    // down: locality 50 -> k=1024
    posatt(curH, oth, m0, down_r, down_w, 1024);
    { float* tmp = curH; curH = oth; oth = tmp; }

    // block 0: PA uses locality 50 -> k=1024
    posatt(curH, oth, m1, pa0_r, pa0_w, 1024);
    gemm(curH, w0_w, w0_b, nullptr, T3, 0, 0);
    gemm(oth, mlp0_w1, mlp0_b1, nullptr, T1, 1, 0);
    gemm(T1, mlp0_w2, mlp0_b2, T3, oth, 1, 0);
    { float* tmp = curH; curH = oth; oth = tmp; }

    // block 1: PA uses locality 30 -> k=615
    posatt(curH, oth, m2, pa1_r, pa1_w, 615);
    gemm(curH, w1_w, w1_b, nullptr, T3, 0, 0);
    gemm(oth, mlp1_w1, mlp1_b1, nullptr, T1, 1, 0);
    gemm(T1, mlp1_w2, mlp1_b2, T3, oth, 1, 0);
    { float* tmp = curH; curH = oth; oth = tmp; }

    // up: locality 80 -> k=1638
    posatt(curH, oth, m3, up_r, up_w, 1638);
    { float* tmp = curH; curH = oth; oth = tmp; }

    gemm(curH, de1_w, de1_b, nullptr, T1, 1, 0);
    hipLaunchKernelGGL(k_decode, dim3(2048), dim3(256), 0, stream, T1, de2_w, de2_b, out);
}

// Round 11
// 843.986 us; speedup vs baseline: 1.0478x; 1.0478x over previous
//
#include <hip/hip_runtime.h>

#define NB 4
#define NN 2048
#define HIDDEN 256
#define NH 8
#define VD 32

typedef float f4 __attribute__((ext_vector_type(4)));

__device__ __forceinline__ float gelu_f(float v) {
    return 0.5f * v * (1.0f + erff(v * 0.7071067811865475f));
}

// h[b,n,c] = gelu(sum_i x[b,n,i]*w[i,c] + b[c]),  IN_C=3
__global__ void k_encode(const float* __restrict__ x, const float* __restrict__ w,
                         const float* __restrict__ b, float* __restrict__ out) {
    int id = blockIdx.x * 256 + threadIdx.x;
    int c = id & 255, rn = id >> 8;
    float acc = b[c];
    acc += x[rn * 3 + 0] * w[c] + x[rn * 3 + 1] * w[256 + c] + x[rn * 3 + 2] * w[512 + c];
    out[id] = gelu_f(acc);
}

// Batched over 4 pos-att calls (blockIdx.y = call): per row of m[c], k-th
// smallest (radix select), row min, per-head softmax denom. Inputs only.
__global__ __launch_bounds__(256) void k_thrsel4(
        const float* __restrict__ m0, const float* __restrict__ m1,
        const float* __restrict__ m2, const float* __restrict__ m3,
        const float* __restrict__ r0, const float* __restrict__ r1,
        const float* __restrict__ r2, const float* __restrict__ r3,
        int k0, int k1, int k2, int k3,
        float* __restrict__ thr, float* __restrict__ mmin, float* __restrict__ invD)
{
    __shared__ float rowf[NN];
    __shared__ unsigned hist[256];
    __shared__ float redf[32];
    __shared__ unsigned redu[4];
    __shared__ unsigned s_bin, s_below;
    const int row = blockIdx.x, t = threadIdx.x;
    const int c = blockIdx.y;
    const int lane = t & 63, wid = t >> 6;
    const float* mb = (c == 0) ? m0 : (c == 1) ? m1 : (c == 2) ? m2 : m3;
    const float* rv = (c == 0) ? r0 : (c == 1) ? r1 : (c == 2) ? r2 : r3;
    const int kcount = (c == 0) ? k0 : (c == 1) ? k1 : (c == 2) ? k2 : k3;
    const float* mr = mb + (size_t)row * NN;

    float lmin = 3.4e38f;
    for (int i = t; i < NN; i += 256) { float v = mr[i]; rowf[i] = v; lmin = fminf(lmin, v); }
#pragma unroll
    for (int d = 32; d > 0; d >>= 1) lmin = fminf(lmin, __shfl_xor(lmin, d, 64));
    if (lane == 0) redf[wid] = lmin;
    __syncthreads();
    const float rmin = fminf(fminf(redf[0], redf[1]), fminf(redf[2], redf[3]));

    unsigned prefix = 0; int want = kcount;
    const unsigned hmasks[4] = {0u, 0xFF000000u, 0xFFFF0000u, 0xFFFFFF00u};
    for (int pass = 0; pass < 4; ++pass) {
        const int shift = 24 - 8 * pass;
        hist[t] = 0;
        __syncthreads();
        const unsigned hm = hmasks[pass];
        for (int i = t; i < NN; i += 256) {
            unsigned u = __float_as_uint(rowf[i]);
            u ^= (u & 0x80000000u) ? 0xFFFFFFFFu : 0x80000000u;
            if ((u & hm) == (prefix & hm))
                atomicAdd(&hist[(u >> shift) & 255u], 1u);
        }
        __syncthreads();
        const unsigned cnt = hist[t];
        unsigned v = cnt;
#pragma unroll
        for (int d = 1; d < 64; d <<= 1) {
            unsigned o = __shfl_up(v, d, 64);
            if (lane >= d) v += o;
        }
        if (lane == 63) redu[wid] = v;
        __syncthreads();
        unsigned woff = 0;
#pragma unroll
        for (int w = 0; w < 3; w++) if (w < wid) woff += redu[w];
        const unsigned incl = v + woff;
        const unsigned below = incl - cnt;
        if (incl >= (unsigned)want && below < (unsigned)want) { s_bin = (unsigned)t; s_below = below; }
        __syncthreads();
        want -= (int)s_below;
        prefix |= (s_bin << shift);
    }
    unsigned ku = prefix;
    ku = (ku & 0x80000000u) ? (ku & 0x7FFFFFFFu) : ~ku;
    const float tf = __uint_as_float(ku);

    const float cc = (float)(0.25 * 3.141592653589793 * (1.0 - 1e-7));
    float sch[NH], lacc[NH];
#pragma unroll
    for (int h = 0; h < NH; h++) { sch[h] = tanf(cc * (1.0f + sinf(rv[h]))); lacc[h] = 0.f; }
    for (int i = t; i < NN; i += 256) {
        float v = rowf[i];
        if (v <= tf) {
            float d = v - rmin;
#pragma unroll
            for (int h = 0; h < NH; h++) lacc[h] += expf(-sch[h] * d);
        }
    }
#pragma unroll
    for (int h = 0; h < NH; h++) {
#pragma unroll
        for (int d = 32; d > 0; d >>= 1) lacc[h] += __shfl_xor(lacc[h], d, 64);
    }
    if (lane == 0) {
#pragma unroll
        for (int h = 0; h < NH; h++) redf[wid * 8 + h] = lacc[h];
    }
    __syncthreads();
    if (t < NH)
        invD[(c * NH + t) * NN + row] = 1.0f / (redf[t] + redf[8 + t] + redf[16 + t] + redf[24 + t]);
    if (t == 0) { thr[c * NN + row] = tf; mmin[c * NN + row] = rmin; }
}

// ---------- legacy 64x64 GEMM (fallback when workspace is small) ----------
__global__ __launch_bounds__(256) void k_gemm(const float* __restrict__ A,
        const float* __restrict__ Wm, const float* __restrict__ bias,
        const float* __restrict__ addsrc, float* __restrict__ Cm, int act, int wmode)
{
    __shared__ float AsT[64 * 68];
    __shared__ float Ws[64 * 68];
    const int r0 = blockIdx.x * 64;
    const int c0 = blockIdx.y * 64;
    const int t = threadIdx.x;
    const int ty = t >> 4, tx = t & 15;
    float acc[4][4] = {};
    for (int k0 = 0; k0 < 256; k0 += 64) {
        __syncthreads();
#pragma unroll
        for (int l = 0; l < 16; l++) {
            int lin = l * 256 + t;
            int rr = lin >> 6, kk = lin & 63;
            AsT[kk * 68 + rr] = A[(size_t)(r0 + rr) * 256 + k0 + kk];
            Ws[rr * 68 + kk] = wmode
                ? Wm[(size_t)((c0 + kk) >> 5) * (HIDDEN * VD) + (size_t)(k0 + rr) * VD + ((c0 + kk) & 31)]
                : Wm[(size_t)(k0 + rr) * 256 + c0 + kk];
        }
        __syncthreads();
#pragma unroll 8
        for (int kk = 0; kk < 64; kk++) {
            const float4 a4 = *(const float4*)&AsT[kk * 68 + ty * 4];
            const float4 w4 = *(const float4*)&Ws[kk * 68 + tx * 4];
            float av[4] = {a4.x, a4.y, a4.z, a4.w};
            float wv[4] = {w4.x, w4.y, w4.z, w4.w};
#pragma unroll
            for (int q = 0; q < 4; q++)
#pragma unroll
                for (int p = 0; p < 4; p++)
                    acc[q][p] = fmaf(av[q], wv[p], acc[q][p]);
        }
    }
#pragma unroll
    for (int q = 0; q < 4; q++) {
        int r = r0 + ty * 4 + q;
#pragma unroll
        for (int p = 0; p < 4; p++) {
            int c = c0 + tx * 4 + p;
            float v = acc[q][p];
            if (bias) v += bias[c];
            if (addsrc) v += addsrc[(size_t)r * 256 + c];
            if (act) v = gelu_f(v);
            Cm[(size_t)r * 256 + c] = v;
        }
    }
}

// ---------- split-K GEMM, LEGACY structure (no prefetch registers) ----------
// (r5-r9 lesson: prefetch-register skeleton trips a 128-VGPR allocator cliff
//  -> scratch spill, ~650 MB/dispatch HBM traffic. Stage-direct-to-LDS never
//  spills. Keep this structure.)
template<int WMODE>
__global__ __launch_bounds__(256) void k_gemm9(const float* __restrict__ A,
        const float* __restrict__ Wm, float* __restrict__ G0, float* __restrict__ G1)
{
    __shared__ float AsT[64 * 68];
    __shared__ float Ws[64 * 68];
    const int r0 = blockIdx.x * 64;
    const int c0 = blockIdx.y * 64;
    const int kbase = blockIdx.z * 128;
    float* __restrict__ G = blockIdx.z ? G1 : G0;
    const int t = threadIdx.x;
    const int ty = t >> 4, tx = t & 15;
    float acc[4][4] = {};
    for (int kh = 0; kh < 128; kh += 64) {
        const int k0 = kbase + kh;
        __syncthreads();
#pragma unroll
        for (int l = 0; l < 16; l++) {
            int lin = l * 256 + t;
            int rr = lin >> 6, kk = lin & 63;
            AsT[kk * 68 + rr] = A[(size_t)(r0 + rr) * 256 + k0 + kk];
            Ws[rr * 68 + kk] = WMODE
                ? Wm[(size_t)((c0 + kk) >> 5) * (HIDDEN * VD) + (size_t)(k0 + rr) * VD + ((c0 + kk) & 31)]
                : Wm[(size_t)(k0 + rr) * 256 + c0 + kk];
        }
        __syncthreads();
#pragma unroll 8
        for (int kk = 0; kk < 64; kk++) {
            const float4 a4 = *(const float4*)&AsT[kk * 68 + ty * 4];
            const float4 w4 = *(const float4*)&Ws[kk * 68 + tx * 4];
            float av[4] = {a4.x, a4.y, a4.z, a4.w};
            float wv[4] = {w4.x, w4.y, w4.z, w4.w};
#pragma unroll
            for (int q = 0; q < 4; q++)
#pragma unroll
                for (int p = 0; p < 4; p++)
                    acc[q][p] = fmaf(av[q], wv[p], acc[q][p]);
        }
    }
#pragma unroll
    for (int q = 0; q < 4; q++) {
        const int r = r0 + ty * 4 + q;
        f4 st;
#pragma unroll
        for (int p = 0; p < 4; p++) st[p] = acc[q][p];
        *(f4*)&G[(size_t)r * 256 + c0 + tx * 4] = st;
    }
}

// out = act(g0 + g1 + bias + addsrc)
__global__ __launch_bounds__(256) void k_gemmcomb(const float* __restrict__ g0,
        const float* __restrict__ g1, const float* __restrict__ bias,
        const float* __restrict__ addsrc, float* __restrict__ out, int act)
{
    int gid = blockIdx.x * 256 + threadIdx.x;
    int idx = gid * 4;
    int c = idx & 255;
    f4 a = *(const f4*)&g0[idx];
    f4 b = *(const f4*)&g1[idx];
    f4 s;
#pragma unroll
    for (int k = 0; k < 4; k++) s[k] = a[k] + b[k];
    if (bias) {
        f4 bb = *(const f4*)&bias[c];
#pragma unroll
        for (int k = 0; k < 4; k++) s[k] += bb[k];
    }
    if (addsrc) {
        f4 r = *(const f4*)&addsrc[idx];
#pragma unroll
        for (int k = 0; k < 4; k++) s[k] += r[k];
    }
    if (act) {
#pragma unroll
        for (int k = 0; k < 4; k++) s[k] = gelu_f(s[k]);
    }
    *(f4*)&out[idx] = s;
}

// ---------- att-apply: STATIC double-buffered LDS, one barrier per tile ----
// grid: (head*16 + itile, jsplit), 256 threads, i-tile=128, acc 8x8/thread.
// LDS = 2*(Es[128][36] + Vs[32][132]) = 70.7 KB -> 2 blocks/CU.
// All buffer selection is compile-time (named arrays, 2-step unrolled loop)
// to avoid the r5 runtime-indexed spill trap.
#define TJA 32
__global__ __launch_bounds__(256, 2) void k_attapply8(
    const float* __restrict__ m, const float* __restrict__ v2,
    const float* __restrict__ rv, const float* __restrict__ thr,
    const float* __restrict__ mmin,
    float* __restrict__ P0, float* __restrict__ P1,
    float* __restrict__ P2, float* __restrict__ P3, int jlen)
{
    __shared__ float EsA[128 * 36];   // [ii][jj], stride 36
    __shared__ float VsA[TJA * 132];  // [jj][col], stride 132
    __shared__ float EsB[128 * 36];
    __shared__ float VsB[TJA * 132];
    const int head = blockIdx.x >> 4;
    const int i0 = (blockIdx.x & 15) * 128;
    const int jbase = blockIdx.y * jlen;
    const int by = blockIdx.y;
    float* __restrict__ P = (by == 0) ? P0 : (by == 1) ? P1 : (by == 2) ? P2 : P3;
    const int t = threadIdx.x;
    const int tx = t & 15, ty = t >> 4;     // compute: cols {4tx,64+4tx}, rows q*16+ty
    const int txm = t & 7, tym = t >> 3;    // E staging: rows q*32+tym, j 4txm
    const int c4 = t & 31, jw = t >> 5;     // V staging
    const int bbv = c4 >> 3, kkv = (c4 & 7) * 4;
    const float cc = (float)(0.25 * 3.141592653589793 * (1.0 - 1e-7));
    const float scale = tanf(cc * (1.0f + sinf(rv[head])));

    float thr_r[4], mmn_r[4];
#pragma unroll
    for (int q = 0; q < 4; q++) {
        thr_r[q] = thr[i0 + q * 32 + tym];
        mmn_r[q] = mmin[i0 + q * 32 + tym];
    }

    float acc[8][8];
#pragma unroll
    for (int q = 0; q < 8; q++)
#pragma unroll
        for (int p = 0; p < 8; p++) acc[q][p] = 0.f;

    f4 pm[4], pv[4];
    const int NT = jlen / TJA;   // 16 at JS=4 (even)

#define A_LOAD(S)                                                              \
    do {                                                                       \
        const int j0 = jbase + (S) * TJA;                                      \
        _Pragma("unroll")                                                      \
        for (int q = 0; q < 4; q++)                                            \
            pm[q] = *(const f4*)&m[(size_t)(i0 + q * 32 + tym) * NN + j0 + 4 * txm]; \
        _Pragma("unroll")                                                      \
        for (int l = 0; l < 4; l++)                                            \
            pv[l] = *(const f4*)&v2[(((size_t)bbv * NN) + j0 + l * 8 + jw) * HIDDEN + head * VD + kkv]; \
    } while (0)

#define A_STORE(ES, VS)                                                        \
    do {                                                                       \
        _Pragma("unroll")                                                      \
        for (int q = 0; q < 4; q++) {                                          \
            f4 ev;                                                             \
            _Pragma("unroll")                                                  \
            for (int d = 0; d < 4; d++) {                                      \
                float e = 0.f;                                                 \
                if (pm[q][d] <= thr_r[q]) e = expf(-scale * (pm[q][d] - mmn_r[q])); \
                ev[d] = e;                                                     \
            }                                                                  \
            *(f4*)&ES[(q * 32 + tym) * 36 + 4 * txm] = ev;                     \
        }                                                                      \
        _Pragma("unroll")                                                      \
        for (int l = 0; l < 4; l++)                                            \
            *(f4*)&VS[(l * 8 + jw) * 132 + 4 * c4] = pv[l];                    \
    } while (0)

#define A_COMPUTE(ES, VS)                                                      \
    do {                                                                       \
        for (int jc = 0; jc < TJA; jc += 4) {                                  \
            f4 ev[8], va[4], vb[4];                                            \
            _Pragma("unroll")                                                  \
            for (int q = 0; q < 8; q++)                                        \
                ev[q] = *(const f4*)&ES[(q * 16 + ty) * 36 + jc];              \
            _Pragma("unroll")                                                  \
            for (int d = 0; d < 4; d++) {                                      \
                va[d] = *(const f4*)&VS[(jc + d) * 132 + 4 * tx];              \
                vb[d] = *(const f4*)&VS[(jc + d) * 132 + 64 + 4 * tx];         \
            }                                                                  \
            _Pragma("unroll")                                                  \
            for (int d = 0; d < 4; d++) {                                      \
                _Pragma("unroll")                                              \
                for (int q = 0; q < 8; q++) {                                  \
                    const float e = ev[q][d];                                  \
                    _Pragma("unroll")                                          \
                    for (int p = 0; p < 4; p++) {                              \
                        acc[q][p]     = fmaf(e, va[d][p], acc[q][p]);          \
                        acc[q][p + 4] = fmaf(e, vb[d][p], acc[q][p + 4]);      \
                    }                                                          \
                }                                                              \
            }                                                                  \
        }                                                                      \
    } while (0)

    A_LOAD(0);
    A_STORE(EsA, VsA);
    __syncthreads();

    for (int s = 0; s < NT; s += 2) {
        if (s + 1 < NT) A_LOAD(s + 1);
        A_COMPUTE(EsA, VsA);
        if (s + 1 < NT) {
            A_STORE(EsB, VsB);
            __syncthreads();
        }
        if (s + 2 < NT) A_LOAD(s + 2);
        if (s + 1 < NT) A_COMPUTE(EsB, VsB);
        if (s + 2 < NT) {
            A_STORE(EsA, VsA);
            __syncthreads();
        }
    }
#undef A_LOAD
#undef A_STORE
#undef A_COMPUTE

    const int bba = tx >> 3, kka = (tx & 7) * 4;
#pragma unroll
    for (int q = 0; q < 8; q++) {
        const int gi = i0 + q * 16 + ty;
        f4 sa, sb;
#pragma unroll
        for (int p = 0; p < 4; p++) { sa[p] = acc[q][p]; sb[p] = acc[q][p + 4]; }
        *(f4*)&P[(((size_t)bba * NN) + gi) * HIDDEN + head * VD + kka] = sa;
        *(f4*)&P[(((size_t)(bba + 2) * NN) + gi) * HIDDEN + head * VD + kka] = sb;
    }
}

// io = gelu((io + p1 [+ p2 + p3]) * invD[h,i])
__global__ __launch_bounds__(256) void k_attcombine(const float* __restrict__ p1,
        const float* __restrict__ p2, const float* __restrict__ p3,
        const float* __restrict__ invD, float* __restrict__ io)
{
    int gid = blockIdx.x * 256 + threadIdx.x;
    int idx = gid * 4;
    int hid = idx & (HIDDEN - 1);
    int i = (idx >> 8) & (NN - 1);
    float sD = invD[(hid >> 5) * NN + i];
    f4 a = *(const f4*)&io[idx];
    f4 b = *(const f4*)&p1[idx];
    f4 s;
#pragma unroll
    for (int k = 0; k < 4; k++) s[k] = a[k] + b[k];
    if (p2) {
        f4 c = *(const f4*)&p2[idx];
        f4 d = *(const f4*)&p3[idx];
#pragma unroll
        for (int k = 0; k < 4; k++) s[k] += c[k] + d[k];
    }
#pragma unroll
    for (int k = 0; k < 4; k++) s[k] = gelu_f(s[k] * sD);
    *(f4*)&io[idx] = s;
}

// out[row] = sum_c A[row,c]*w[c] + b   (one wave per row)
__global__ void k_decode(const float* __restrict__ a, const float* __restrict__ w,
                         const float* __restrict__ b, float* __restrict__ out) {
    int gid = blockIdx.x * 256 + threadIdx.x;
    int row = gid >> 6, lane = threadIdx.x & 63;
    const float* ar = a + (size_t)row * HIDDEN;
    float s = ar[lane] * w[lane] + ar[lane + 64] * w[lane + 64]
            + ar[lane + 128] * w[lane + 128] + ar[lane + 192] * w[lane + 192];
    for (int off = 32; off > 0; off >>= 1) s += __shfl_down(s, off);
    if (lane == 0) out[row] = s + b[0];
}

extern "C" void kernel_launch(void* const* d_in, const int* in_sizes, int n_in,
                              void* d_out, int out_size, void* d_ws, size_t ws_size,
                              hipStream_t stream)
{
    (void)in_sizes; (void)n_in; (void)out_size;
    const float* x      = (const float*)d_in[0];
    const float* m0     = (const float*)d_in[1];
    const float* m1     = (const float*)d_in[2];
    const float* m2     = (const float*)d_in[3];
    const float* m3     = (const float*)d_in[4];
    const float* en_w   = (const float*)d_in[5];
    const float* en_b   = (const float*)d_in[6];
    const float* down_r = (const float*)d_in[7];
    const float* down_w = (const float*)d_in[8];
    const float* pa0_r  = (const float*)d_in[9];
    const float* pa0_w  = (const float*)d_in[10];
    const float* pa1_r  = (const float*)d_in[11];
    const float* pa1_w  = (const float*)d_in[12];
    const float* mlp0_w1= (const float*)d_in[13];
    const float* mlp0_b1= (const float*)d_in[14];
    const float* mlp0_w2= (const float*)d_in[15];
    const float* mlp0_b2= (const float*)d_in[16];
    const float* w0_w   = (const float*)d_in[17];
    const float* w0_b   = (const float*)d_in[18];
    const float* mlp1_w1= (const float*)d_in[19];
    const float* mlp1_b1= (const float*)d_in[20];
    const float* mlp1_w2= (const float*)d_in[21];
    const float* mlp1_b2= (const float*)d_in[22];
    const float* w1_w   = (const float*)d_in[23];
    const float* w1_b   = (const float*)d_in[24];
    const float* up_r   = (const float*)d_in[25];
    const float* up_w   = (const float*)d_in[26];
    const float* de1_w  = (const float*)d_in[27];
    const float* de1_b  = (const float*)d_in[28];
    const float* de2_w  = (const float*)d_in[29];
    const float* de2_b  = (const float*)d_in[30];
    float* out = (float*)d_out;

    float* WS = (float*)d_ws;
    const size_t SZ = (size_t)NB * NN * HIDDEN;
    float* Hb   = WS;
    float* Ab   = Hb + SZ;
    float* Vb   = Ab + SZ;
    float* T1   = Vb + SZ;
    float* THR4 = T1 + SZ;          // 4*NN
    float* MMIN4= THR4 + 4 * NN;    // 4*NN
    float* INVD4= MMIN4 + 4 * NN;   // 4*NH*NN
    float* P2   = INVD4 + 4 * NH * NN;
    float* P3   = P2 + SZ;
    const size_t need4 = (size_t)((P3 + SZ) - WS) * sizeof(float);
    const int JS = (ws_size >= need4) ? 4 : 2;
    float* T3   = Vb;               // alias: value buffer dead outside posatt

    // GEMM helper: dst = act(A@W + bias + add); split-K partials in P2/P3
    auto gemm = [&](const float* A, const float* W, const float* bias,
                    const float* add, float* dst, int act, int wmode) {
        if (JS >= 4) {
            if (wmode)
                hipLaunchKernelGGL((k_gemm9<1>), dim3(128, 4, 2), dim3(256), 0, stream,
                                   A, W, P2, P3);
            else
                hipLaunchKernelGGL((k_gemm9<0>), dim3(128, 4, 2), dim3(256), 0, stream,
                                   A, W, P2, P3);
            hipLaunchKernelGGL(k_gemmcomb, dim3((int)(SZ / 4 / 256)), dim3(256), 0, stream,
                               P2, P3, bias, add, dst, act);
        } else {
            hipLaunchKernelGGL(k_gemm, dim3(128, 4), dim3(256), 0, stream,
                               A, W, bias, add, dst, act, wmode);
        }
    };

    // all 4 threshold computations depend only on inputs -> one batched dispatch
    hipLaunchKernelGGL(k_thrsel4, dim3(NN, 4), dim3(256), 0, stream,
                       m0, m1, m2, m3, down_r, pa0_r, pa1_r, up_r,
                       1024, 1024, 615, 1638, THR4, MMIN4, INVD4);

    auto posatt = [&](int c, const float* src, float* dst2, const float* md,
                      const float* r, const float* w) {
        gemm(src, w, nullptr, nullptr, Vb, 0, 1);
        hipLaunchKernelGGL(k_attapply8, dim3(128, JS), dim3(256), 0, stream,
                           md, Vb, r, THR4 + c * NN, MMIN4 + c * NN,
                           dst2, T1, P2, P3, NN / JS);
        hipLaunchKernelGGL(k_attcombine, dim3((int)(SZ / 4 / 256)), dim3(256), 0, stream,
                           T1, (JS >= 4) ? P2 : (const float*)nullptr,
                           (JS >= 4) ? P3 : (const float*)nullptr,
                           INVD4 + c * NH * NN, dst2);
    };

    float* curH = Hb; float* oth = Ab;
    hipLaunchKernelGGL(k_encode, dim3(8192), dim3(256), 0, stream, x, en_w, en_b, curH);

    // down: locality 50 -> k=1024
    posatt(0, curH, oth, m0, down_r, down_w);
    { float* tmp = curH; curH = oth; oth = tmp; }

    // block 0: PA uses locality 50 -> k=1024
    posatt(1, curH, oth, m1, pa0_r, pa0_w);
    gemm(curH, w0_w, w0_b, nullptr, T3, 0, 0);
    gemm(oth, mlp0_w1, mlp0_b1, nullptr, T1, 1, 0);
    gemm(T1, mlp0_w2, mlp0_b2, T3, oth, 1, 0);
    { float* tmp = curH; curH = oth; oth = tmp; }

    // block 1: PA uses locality 30 -> k=615
    posatt(2, curH, oth, m2, pa1_r, pa1_w);
    gemm(curH, w1_w, w1_b, nullptr, T3, 0, 0);
    gemm(oth, mlp1_w1, mlp1_b1, nullptr, T1, 1, 0);
    gemm(T1, mlp1_w2, mlp1_b2, T3, oth, 1, 0);
    { float* tmp = curH; curH = oth; oth = tmp; }

    // up: locality 80 -> k=1638
    posatt(3, curH, oth, m3, up_r, up_w);
    { float* tmp = curH; curH = oth; oth = tmp; }

    gemm(curH, de1_w, de1_b, nullptr, T1, 1, 0);
    hipLaunchKernelGGL(k_decode, dim3(2048), dim3(256), 0, stream, T1, de2_w, de2_b, out);
}